// Round 2
// baseline (193.113 us; speedup 1.0000x reference)
//
#include <hip/hip_runtime.h>
#include <hip/hip_bf16.h>

// SubnetGate = gathered grouped GEMM.
// B=16384 rows, K=512, N=512, E=8 experts, G=2 (col 0 used).
// Plan: bucket rows by expert, cast to bf16, MFMA 16x16x32.
//
// ws layout:
//   [0,        32)        int counts[8]
//   [4096,     528384)    int rowlist[8][16384]
//   [528384,   4722688)   ushort Wt[8][512][512]  (W transposed: [e][n][k], bf16)

#define NROWS   16384
#define KDIM    512
#define NDIM    512
#define NEXP    8
#define WS_ROWLIST_OFF 4096
#define WS_WT_OFF      (4096 + NEXP * NROWS * 4)

typedef __bf16        bf16x8 __attribute__((ext_vector_type(8)));
typedef float         f32x4  __attribute__((ext_vector_type(4)));
typedef unsigned int  u32x4  __attribute__((ext_vector_type(4)));

__device__ __forceinline__ unsigned int f2bf_u(float f) {
    // round-to-nearest-even f32 -> bf16 (as 16-bit value)
    unsigned int u = __builtin_bit_cast(unsigned int, f);
    return (u + 0x7FFFu + ((u >> 16) & 1u)) >> 16;
}

__global__ void zero_kernel(int* __restrict__ gcnt) {
    if (threadIdx.x < NEXP) gcnt[threadIdx.x] = 0;
}

// blocks [0,512): transpose+cast one 64x64 tile of W into Wt[e][n][k] bf16.
// blocks [512,576): histogram+scatter 256 rows each into per-expert rowlists.
__global__ void prep_kernel(const float* __restrict__ W,
                            const int* __restrict__ groups,
                            int* __restrict__ gcnt,
                            int* __restrict__ rowlist,
                            unsigned short* __restrict__ Wt) {
    __shared__ unsigned short tl[64 * 66];   // pad 66: bank stride 33 dwords -> 2-way max
    __shared__ int lcnt[NEXP];
    __shared__ int lbase[NEXP];
    const int bid = blockIdx.x;
    const int tid = threadIdx.x;

    if (bid < 512) {
        const int e  = bid >> 6;
        const int ot = (bid >> 3) & 7;   // n-tile
        const int it = bid & 7;          // k-tile
        const float*          Wb  = W  + (size_t)e * (KDIM * NDIM);
        unsigned short*       Wtb = Wt + (size_t)e * (KDIM * NDIM);
        #pragma unroll
        for (int itr = 0; itr < 16; ++itr) {
            int f = itr * 256 + tid;
            int r = f >> 6, c = f & 63;              // r: k-local, c: n-local (coalesced in n)
            tl[r * 66 + c] =
                (unsigned short)f2bf_u(Wb[(size_t)(it * 64 + r) * NDIM + ot * 64 + c]);
        }
        __syncthreads();
        #pragma unroll
        for (int itr = 0; itr < 16; ++itr) {
            int f = itr * 256 + tid;
            int r2 = f >> 6, c2 = f & 63;            // r2: n-local, c2: k-local (coalesced in k)
            Wtb[(size_t)(ot * 64 + r2) * KDIM + it * 64 + c2] = tl[c2 * 66 + r2];
        }
    } else {
        const int base = (bid - 512) * 256;
        if (tid < NEXP) lcnt[tid] = 0;
        __syncthreads();
        int r = base + tid;
        int e = groups[r * 2];                        // group_col = 0
        int pos = atomicAdd(&lcnt[e], 1);
        __syncthreads();
        if (tid < NEXP) lbase[tid] = atomicAdd(&gcnt[tid], lcnt[tid]);
        __syncthreads();
        rowlist[e * NROWS + lbase[e] + pos] = r;
    }
}

// One block = (expert e, row-tile t of 64 gathered rows).
// A (64 x 512, bf16) resident in LDS for full K, XOR-swizzled 16B granules.
// 4 waves own disjoint 32-col strips per 128-col n-window -> B frags straight
// from global (L2-resident Wt), no k-loop barriers at all.
__global__ __launch_bounds__(256, 2)
void gemm_kernel(const float* __restrict__ x,
                 const int* __restrict__ counts,
                 const int* __restrict__ rowlist,
                 const unsigned short* __restrict__ Wt,
                 const float* __restrict__ bias,
                 float* __restrict__ out) {
    __shared__ __align__(16) unsigned short A[64 * KDIM];   // 64 KB

    const int bid = blockIdx.x;
    const int e   = bid >> 8;
    const int t   = bid & 255;
    const int cnt = counts[e];
    const int rb  = t << 6;
    if (rb >= cnt) return;
    int m_valid = cnt - rb;
    if (m_valid > 64) m_valid = 64;
    const int* rl = rowlist + e * NROWS + rb;

    const int tid = threadIdx.x;
    const int w   = tid >> 6;
    const int ln  = tid & 63;
    const int q   = ln >> 4;
    const int l15 = ln & 15;

    // ---- stage A: gathered f32 rows -> bf16 LDS, granule (m,ka) at m*64+(ka^m)
    #pragma unroll
    for (int itr = 0; itr < 16; ++itr) {
        int f  = itr * 256 + tid;
        int m  = f >> 6;
        int ka = f & 63;
        u32x4 pack = {0u, 0u, 0u, 0u};
        if (m < m_valid) {
            int row = rl[m];
            const float* src = x + (size_t)row * KDIM + ka * 8;
            f32x4 f0 = *(const f32x4*)src;
            f32x4 f1 = *(const f32x4*)(src + 4);
            pack.x = f2bf_u(f0.x) | (f2bf_u(f0.y) << 16);
            pack.y = f2bf_u(f0.z) | (f2bf_u(f0.w) << 16);
            pack.z = f2bf_u(f1.x) | (f2bf_u(f1.y) << 16);
            pack.w = f2bf_u(f1.z) | (f2bf_u(f1.w) << 16);
        }
        *(u32x4*)&A[(m * 64 + (ka ^ m)) * 8] = pack;
    }
    __syncthreads();

    // global row index per output slot (C/D: row = q*4 + r within 16x16 tile)
    int grow[16];
    #pragma unroll
    for (int mi = 0; mi < 4; ++mi)
        #pragma unroll
        for (int r = 0; r < 4; ++r) {
            int rloc = mi * 16 + q * 4 + r;
            grow[mi * 4 + r] = (rloc < m_valid) ? rl[rloc] : -1;
        }

    const unsigned short* We = Wt + (size_t)e * (KDIM * NDIM);

    for (int j = 0; j < 4; ++j) {
        const int nc0 = j * 128 + w * 32;
        f32x4 acc[4][2];
        #pragma unroll
        for (int mi = 0; mi < 4; ++mi)
            #pragma unroll
            for (int ni = 0; ni < 2; ++ni)
                acc[mi][ni] = (f32x4){0.f, 0.f, 0.f, 0.f};

        #pragma unroll
        for (int ks = 0; ks < 16; ++ks) {
            bf16x8 af[4];
            #pragma unroll
            for (int mi = 0; mi < 4; ++mi) {
                int m  = mi * 16 + l15;
                int ka = ks * 4 + q;
                af[mi] = *(const bf16x8*)&A[(m * 64 + (ka ^ m)) * 8];
            }
            bf16x8 bfr[2];
            #pragma unroll
            for (int ni = 0; ni < 2; ++ni) {
                int n = nc0 + ni * 16 + l15;
                bfr[ni] = *(const bf16x8*)(We + (size_t)n * KDIM + ks * 32 + q * 8);
            }
            #pragma unroll
            for (int mi = 0; mi < 4; ++mi)
                #pragma unroll
                for (int ni = 0; ni < 2; ++ni)
                    acc[mi][ni] = __builtin_amdgcn_mfma_f32_16x16x32_bf16(
                        af[mi], bfr[ni], acc[mi][ni], 0, 0, 0);
        }

        // epilogue: + bias, masked scatter store (each out row written once)
        #pragma unroll
        for (int ni = 0; ni < 2; ++ni) {
            int col = nc0 + ni * 16 + l15;
            float bv = bias[e * NDIM + col];
            #pragma unroll
            for (int mi = 0; mi < 4; ++mi) {
                #pragma unroll
                for (int r = 0; r < 4; ++r) {
                    int g = grow[mi * 4 + r];
                    if (g >= 0) out[(size_t)g * NDIM + col] = acc[mi][ni][r] + bv;
                }
            }
        }
    }
}

extern "C" void kernel_launch(void* const* d_in, const int* in_sizes, int n_in,
                              void* d_out, int out_size, void* d_ws, size_t ws_size,
                              hipStream_t stream) {
    const float* x      = (const float*)d_in[0];   // (16384, 512) f32
    const int*   groups = (const int*)d_in[1];     // (16384, 2) i32
    const float* W      = (const float*)d_in[2];   // (8, 512, 512) f32
    const float* b      = (const float*)d_in[3];   // (8, 512) f32
    float*       out    = (float*)d_out;           // (16384, 512) f32

    char* ws = (char*)d_ws;
    int*            counts  = (int*)ws;
    int*            rowlist = (int*)(ws + WS_ROWLIST_OFF);
    unsigned short* Wt      = (unsigned short*)(ws + WS_WT_OFF);

    zero_kernel<<<1, 64, 0, stream>>>(counts);
    prep_kernel<<<576, 256, 0, stream>>>(W, groups, counts, rowlist, Wt);
    gemm_kernel<<<2048, 256, 0, stream>>>(x, counts, rowlist, Wt, b, out);
}

// Round 3
// 127.430 us; speedup vs baseline: 1.5154x; 1.5154x over previous
//
#include <hip/hip_runtime.h>
#include <hip/hip_bf16.h>

// SubnetGate = gathered grouped GEMM (B=16384, K=512, N=512, E=8, col 0).
// R2 redesign: m97-style 128x128x64 MFMA tiles, async global_load_lds for B
// (pre-swizzled tiled weight layout), 4x working blocks vs R0.
//
// ws layout:
//   [0,        32)        int counts[8]
//   [4096,     528384)    int rowlist[8][16384]
//   [528384,   4722688)   ushort Wtile[8][4 nt][8 kt][128n x 64k bf16, swizzled]

#define NROWS   16384
#define KDIM    512
#define NDIM    512
#define NEXP    8
#define BM      128
#define BN      128
#define BK      64
#define NT_PER  4
#define KT_PER  8
#define TILE_ELEMS (BN * BK)          // 8192 bf16 = 16KB
#define WS_ROWLIST_OFF 4096
#define WS_WT_OFF      (4096 + NEXP * NROWS * 4)

typedef __bf16        bf16x8 __attribute__((ext_vector_type(8)));
typedef float         f32x4  __attribute__((ext_vector_type(4)));
typedef unsigned int  u32x4  __attribute__((ext_vector_type(4)));

__device__ __forceinline__ unsigned int f2bf_u(float f) {
    unsigned int u = __builtin_bit_cast(unsigned int, f);
    return (u + 0x7FFFu + ((u >> 16) & 1u)) >> 16;   // RNE f32->bf16
}

__device__ __forceinline__ void gl_lds16(const void* g, void* l) {
    __builtin_amdgcn_global_load_lds(
        (const __attribute__((address_space(1))) unsigned int*)g,
        (__attribute__((address_space(3))) unsigned int*)l, 16, 0, 0);
}

__global__ void zero_kernel(int* __restrict__ gcnt) {
    if (threadIdx.x < NEXP) gcnt[threadIdx.x] = 0;
}

// blocks [0,256): build one 16KB swizzled B-tile (e,nt,kt).
//   granule (n in 0..127, g in 0..7) holds W[e][kt*64+g*8 .. +8][nt*128+n] bf16,
//   stored at tile byte offset n*128 + (g^(n&7))*16  (conflict-free frag reads).
// blocks [256,320): histogram+scatter 256 rows each into per-expert rowlists.
__global__ void prep_kernel(const float* __restrict__ W,
                            const int* __restrict__ groups,
                            int* __restrict__ gcnt,
                            int* __restrict__ rowlist,
                            unsigned short* __restrict__ Wtile) {
    __shared__ __align__(16) unsigned short tl[TILE_ELEMS];  // 16KB
    __shared__ int lcnt[NEXP];
    __shared__ int lbase[NEXP];
    const int bid = blockIdx.x;
    const int tid = threadIdx.x;

    if (bid < 256) {
        const int e  = bid >> 5;         // [e][nt][kt] <=> bid = e*32 + nt*8 + kt
        const int nt = (bid >> 3) & 3;
        const int kt = bid & 7;
        const float* Wb = W + (size_t)e * (KDIM * NDIM);
        #pragma unroll
        for (int i = 0; i < 4; ++i) {
            int f = i * 256 + tid;       // granule id 0..1023
            int n = f & 127;             // lanes consecutive n -> coalesced reads
            int g = f >> 7;              // 0..7
            int col = nt * BN + n;
            unsigned int p[4];
            #pragma unroll
            for (int jj = 0; jj < 4; ++jj) {
                int k0 = kt * BK + g * 8 + jj * 2;
                unsigned int lo = f2bf_u(Wb[(size_t)k0 * NDIM + col]);
                unsigned int hi = f2bf_u(Wb[(size_t)(k0 + 1) * NDIM + col]);
                p[jj] = lo | (hi << 16);
            }
            *(u32x4*)&tl[n * 64 + (g ^ (n & 7)) * 8] = *(const u32x4*)p;
        }
        __syncthreads();
        unsigned short* dst = Wtile + (size_t)bid * TILE_ELEMS;
        #pragma unroll
        for (int i = 0; i < 4; ++i) {    // linear, fully coalesced 16B writes
            int off = (i * 256 + tid) * 8;
            *(u32x4*)&dst[off] = *(const u32x4*)&tl[off];
        }
    } else {
        const int base = (bid - 256) * 256;
        if (tid < NEXP) lcnt[tid] = 0;
        __syncthreads();
        int r = base + tid;
        int e = groups[r * 2];           // group_col = 0
        int pos = atomicAdd(&lcnt[e], 1);
        __syncthreads();
        if (tid < NEXP) lbase[tid] = atomicAdd(&gcnt[tid], lcnt[tid]);
        __syncthreads();
        rowlist[e * NROWS + lbase[e] + pos] = r;
    }
}

// Block = (expert e, m-tile of 128 gathered rows, n-tile of 128 cols).
// k-loop: 8 steps of BK=64; B async-staged (global_load_lds x4/thread),
// A gathered f32 -> bf16 -> ds_write_b128 (144B row stride, optimal banks).
// Wave w owns 64x64 quadrant: wm=(w>>1)*64, wn=(w&1)*64; acc 4x4 f32x4.
__global__ __launch_bounds__(256, 2)
void gemm_kernel(const float* __restrict__ x,
                 const int* __restrict__ counts,
                 const int* __restrict__ rowlist,
                 const unsigned short* __restrict__ Wtile,
                 const float* __restrict__ bias,
                 float* __restrict__ out) {
    __shared__ __align__(16) unsigned short Asm[BM * 72];     // 18KB (pad: 72 shorts/row)
    __shared__ __align__(16) unsigned short Bsm[TILE_ELEMS];  // 16KB

    const int bid = blockIdx.x;
    const int e   = bid >> 9;
    const int mt  = (bid >> 2) & 127;
    const int nt  = bid & 3;
    const int cnt = counts[e];
    const int rb  = mt * BM;
    if (rb >= cnt) return;
    int m_valid = cnt - rb;
    if (m_valid > BM) m_valid = BM;
    const int* rl = rowlist + e * NROWS + rb;

    const int tid = threadIdx.x;
    const int w   = tid >> 6;
    const int ln  = tid & 63;
    const int q   = ln >> 4;
    const int l15 = ln & 15;
    const int wm  = (w >> 1) * 64;
    const int wn  = (w & 1) * 64;

    // A-staging assignments: granule f=(i*256+tid): m=f>>3, g=f&7
    const float* srcp[4];
    #pragma unroll
    for (int i = 0; i < 4; ++i) {
        int f = i * 256 + tid;
        int m = f >> 3;
        int g = f & 7;
        srcp[i] = (m < m_valid) ? (x + (size_t)rl[m] * KDIM + g * 8) : nullptr;
    }

    const unsigned short* wt =
        Wtile + (size_t)((e * NT_PER + nt) * KT_PER) * TILE_ELEMS;

    f32x4 acc[4][4];
    #pragma unroll
    for (int mi = 0; mi < 4; ++mi)
        #pragma unroll
        for (int ni = 0; ni < 4; ++ni)
            acc[mi][ni] = (f32x4){0.f, 0.f, 0.f, 0.f};

    for (int kt = 0; kt < KT_PER; ++kt) {
        // ---- B stage: async 16B direct-to-LDS (linear; layout pre-swizzled)
        const unsigned short* wsrc = wt + (size_t)kt * TILE_ELEMS;
        #pragma unroll
        for (int i = 0; i < 4; ++i) {
            int off = (i * 256 + tid) * 8;           // shorts
            gl_lds16(wsrc + off, &Bsm[off]);
        }
        // ---- A stage: gathered f32x8 -> bf16x8 -> LDS
        #pragma unroll
        for (int i = 0; i < 4; ++i) {
            int f = i * 256 + tid;
            int m = f >> 3;
            int g = f & 7;
            u32x4 pack = {0u, 0u, 0u, 0u};
            if (srcp[i]) {
                const float* s = srcp[i] + kt * BK;
                f32x4 f0 = *(const f32x4*)s;
                f32x4 f1 = *(const f32x4*)(s + 4);
                pack.x = f2bf_u(f0.x) | (f2bf_u(f0.y) << 16);
                pack.y = f2bf_u(f0.z) | (f2bf_u(f0.w) << 16);
                pack.z = f2bf_u(f1.x) | (f2bf_u(f1.y) << 16);
                pack.w = f2bf_u(f1.z) | (f2bf_u(f1.w) << 16);
            }
            *(u32x4*)&Asm[m * 72 + g * 8] = pack;
        }
        __syncthreads();
        // ---- compute: 2 sub-steps of 16x16x32, 16 MFMA each
        #pragma unroll
        for (int ks = 0; ks < 2; ++ks) {
            const int g = ks * 4 + q;
            bf16x8 af[4], bf[4];
            #pragma unroll
            for (int mi = 0; mi < 4; ++mi)
                af[mi] = *(const bf16x8*)&Asm[(wm + mi * 16 + l15) * 72 + g * 8];
            #pragma unroll
            for (int ni = 0; ni < 4; ++ni) {
                int n = wn + ni * 16 + l15;
                bf[ni] = *(const bf16x8*)&Bsm[n * 64 + (g ^ (n & 7)) * 8];
            }
            #pragma unroll
            for (int mi = 0; mi < 4; ++mi)
                #pragma unroll
                for (int ni = 0; ni < 4; ++ni)
                    acc[mi][ni] = __builtin_amdgcn_mfma_f32_16x16x32_bf16(
                        af[mi], bf[ni], acc[mi][ni], 0, 0, 0);
        }
        __syncthreads();
    }

    // ---- epilogue: +bias, masked scatter (C/D: col=l15, row=q*4+r)
    int growv[16];
    #pragma unroll
    for (int mi = 0; mi < 4; ++mi)
        #pragma unroll
        for (int r = 0; r < 4; ++r) {
            int rloc = wm + mi * 16 + q * 4 + r;
            growv[mi * 4 + r] = (rloc < m_valid) ? rl[rloc] : -1;
        }
    const int ncol0 = nt * BN + wn;
    #pragma unroll
    for (int ni = 0; ni < 4; ++ni) {
        int col = ncol0 + ni * 16 + l15;
        float bv = bias[e * NDIM + col];
        #pragma unroll
        for (int mi = 0; mi < 4; ++mi)
            #pragma unroll
            for (int r = 0; r < 4; ++r) {
                int gr = growv[mi * 4 + r];
                if (gr >= 0) out[(size_t)gr * NDIM + col] = acc[mi][ni][r] + bv;
            }
    }
}

extern "C" void kernel_launch(void* const* d_in, const int* in_sizes, int n_in,
                              void* d_out, int out_size, void* d_ws, size_t ws_size,
                              hipStream_t stream) {
    const float* x      = (const float*)d_in[0];   // (16384, 512) f32
    const int*   groups = (const int*)d_in[1];     // (16384, 2) i32
    const float* W      = (const float*)d_in[2];   // (8, 512, 512) f32
    const float* b      = (const float*)d_in[3];   // (8, 512) f32
    float*       out    = (float*)d_out;           // (16384, 512) f32

    char* ws = (char*)d_ws;
    int*            counts  = (int*)ws;
    int*            rowlist = (int*)(ws + WS_ROWLIST_OFF);
    unsigned short* Wtile   = (unsigned short*)(ws + WS_WT_OFF);

    zero_kernel<<<1, 64, 0, stream>>>(counts);
    prep_kernel<<<320, 256, 0, stream>>>(W, groups, counts, rowlist, Wtile);
    gemm_kernel<<<4096, 256, 0, stream>>>(x, counts, rowlist, Wtile, b, out);
}